// Round 6
// baseline (692.243 us; speedup 1.0000x reference)
//
#include <hip/hip_runtime.h>
#include <hip/hip_fp16.h>
#include <cstdint>
#include <cstddef>

// Problem constants (fixed by the reference)
static constexpr int NN = 100000;   // nodes
static constexpr int NE = 3200000;  // edges
static constexpr int NG = 256;      // graphs
static constexpr int NBK = (NN + 127) / 128;  // dst/src buckets of 128 nodes = 782
static constexpr int EPB = NE / 256;          // edges per hist/scatter block = 12500
static constexpr int GB_BATCH = (NN + 255) / 256;                 // 391
static constexpr int GB_PREPW = (192 * 128 + 64 * 192 + 255) / 256;  // 144
static constexpr int GB_HIST = 256;

typedef _Float16 h8 __attribute__((ext_vector_type(8)));
typedef float f4v __attribute__((ext_vector_type(4)));

__device__ __forceinline__ void atomAddF(float* p, float v) {
  unsafeAtomicAdd(p, v);  // native global_atomic_add_f32 on gfx950
}

union H2 { unsigned u; __half2 h; };
__device__ __forceinline__ float2 up2(unsigned u) {
  H2 c; c.u = u; return __half22float2(c.h);
}
__device__ __forceinline__ unsigned pk2(float a, float b) {
  unsigned lo = __half_as_ushort(__float2half_rn(a));
  unsigned hi = __half_as_ushort(__float2half_rn(b));
  return lo | (hi << 16);
}

// ---------------------------------------------------------------------------
// dtype hedge: reference says int64, harness doc says int32. Detect at runtime.
__global__ void k_detect(const int* __restrict__ ei, int* __restrict__ flag) {
  if (threadIdx.x == 0 && blockIdx.x == 0) {
    int nz = 0;
    for (int i = 0; i < 64; ++i) nz += (ei[2 * i + 1] != 0) ? 1 : 0;
    *flag = (nz == 0) ? 1 : 0;  // 1 => int64 layout
  }
}

__device__ __forceinline__ int ld_idx(const void* raw, int f, int i) {
  return f ? (int)((const long long*)raw)[i] : ((const int*)raw)[i];
}

// ---------------------------------------------------------------------------
// Front kernel: blockIdx ranges -> [batch repack+gcnt | weight prep | edge hist]
__global__ __launch_bounds__(256) void k_front(const void* __restrict__ bat,
                                               const void* __restrict__ ei,
                                               const int* __restrict__ flag,
                                               const float* __restrict__ W1,
                                               const float* __restrict__ W2,
                                               int* __restrict__ b32,
                                               int* __restrict__ gcnt,
                                               __half* __restrict__ BtX,
                                               __half* __restrict__ BtH,
                                               int* __restrict__ sCnt,
                                               int* __restrict__ dCnt,
                                               int* __restrict__ hsBlk,
                                               int* __restrict__ hdBlk) {
  __shared__ int sh[2 * NBK];
  int b = blockIdx.x;
  int t = threadIdx.x;
  if (b < GB_BATCH) {
    // ---- batch repack + graph counts (batch sorted -> per-block runs)
    int* cnt = sh;
    cnt[t] = 0;
    int blk0 = b * 256;
    int f = *flag;
    int g0 = ld_idx(bat, f, blk0);
    __syncthreads();
    int i = blk0 + t;
    if (i < NN) {
      int g = ld_idx(bat, f, i);
      b32[i] = g;
      atomicAdd(&cnt[g - g0], 1);
    }
    __syncthreads();
    if (cnt[t] > 0) atomicAdd(&gcnt[g0 + t], cnt[t]);
  } else if (b < GB_BATCH + GB_PREPW) {
    // ---- weight prep: BtX[192][128], BtH[64][192] fp16, transforms folded
    int u = (b - GB_BATCH) * 256 + t;
    if (u < 192 * 128) {
      int n = u >> 7, k = u & 127;
      float v;
      if (n < 64)       v = W1[k * 64 + n] - W1[16384 + k * 64 + n];
      else if (n < 128) v = W1[8192 + k * 64 + (n - 64)];
      else              v = W1[16384 + k * 64 + (n - 128)];
      BtX[n * 128 + k] = __float2half_rn(v);
    } else if (u < 192 * 128 + 64 * 192) {
      int u2 = u - 192 * 128;
      int n = u2 / 192, k = u2 % 192;
      int s = k >> 6, kk = k & 63;
      float v = (s == 0) ? (W2[kk * 64 + n] - W2[8192 + kk * 64 + n])
              : (s == 1) ? W2[4096 + kk * 64 + n]
                         : 2.f * W2[8192 + kk * 64 + n];
      BtH[n * 192 + k] = __float2half_rn(v);
    }
  } else {
    // ---- edge histogram (per-block hists persisted for k_scatter)
    int hb = b - GB_BATCH - GB_PREPW;
    int* hs = sh;
    int* hd = sh + NBK;
    for (int i = t; i < NBK; i += 256) { hs[i] = 0; hd[i] = 0; }
    __syncthreads();
    int f = *flag;
    int e0 = hb * EPB;
    for (int e = e0 + t; e < e0 + EPB; e += 256) {
      int s = ld_idx(ei, f, e);
      int d = ld_idx(ei, f, NE + e);
      atomicAdd(&hs[s >> 7], 1);
      atomicAdd(&hd[d >> 7], 1);
    }
    __syncthreads();
    size_t hoff = (size_t)hb * NBK;
    for (int i = t; i < NBK; i += 256) {
      int a = hs[i], c = hd[i];
      hsBlk[hoff + i] = a;
      hdBlk[hoff + i] = c;
      if (a) atomicAdd(&sCnt[i], a);
      if (c) atomicAdd(&dCnt[i], c);
    }
  }
}

// Exclusive scan of both bucket-count arrays (782 <= 1024, one block).
__global__ __launch_bounds__(1024) void k_scan(const int* __restrict__ sCnt,
                                               const int* __restrict__ dCnt,
                                               int* __restrict__ sBase,
                                               int* __restrict__ dBase,
                                               int* __restrict__ sCur,
                                               int* __restrict__ dCur) {
  __shared__ int sh1[1024], sh2[1024];
  int t = threadIdx.x;
  int v1 = (t < NBK) ? sCnt[t] : 0;
  int v2 = (t < NBK) ? dCnt[t] : 0;
  sh1[t] = v1; sh2[t] = v2;
  __syncthreads();
  for (int off = 1; off < 1024; off <<= 1) {
    int a1 = (t >= off) ? sh1[t - off] : 0;
    int a2 = (t >= off) ? sh2[t - off] : 0;
    __syncthreads();
    sh1[t] += a1; sh2[t] += a2;
    __syncthreads();
  }
  if (t <= NBK) {
    int b1 = sh1[t] - v1, b2 = sh2[t] - v2;  // exclusive
    sBase[t] = b1; dBase[t] = b2;
    if (t < NBK) { sCur[t] = b1; dCur[t] = b2; }
  }
}

// Pass 2: chunk-reserve per (block,bucket) using saved per-block hists,
// scatter src ids (by src bucket) and packed (src | dst_local<<17) records.
__global__ __launch_bounds__(256) void k_scatter(const void* __restrict__ raw,
                                                 const int* __restrict__ flag,
                                                 const int* __restrict__ hsBlk,
                                                 const int* __restrict__ hdBlk,
                                                 int* __restrict__ sCur,
                                                 int* __restrict__ dCur,
                                                 int* __restrict__ srclist,
                                                 unsigned* __restrict__ elist) {
  __shared__ int hs[NBK], hd[NBK], cbS[NBK], cbD[NBK];
  int t = threadIdx.x;
  size_t hb = (size_t)blockIdx.x * NBK;
  for (int i = t; i < NBK; i += 256) {
    int c1 = hsBlk[hb + i];
    cbS[i] = c1 ? atomicAdd(&sCur[i], c1) : 0;
    int c2 = hdBlk[hb + i];
    cbD[i] = c2 ? atomicAdd(&dCur[i], c2) : 0;
    hs[i] = 0; hd[i] = 0;
  }
  __syncthreads();
  int f = *flag;
  int e0 = blockIdx.x * EPB;
  for (int e = e0 + t; e < e0 + EPB; e += 256) {
    int s = ld_idx(raw, f, e);
    int d = ld_idx(raw, f, NE + e);
    int bs = s >> 7, bd = d >> 7;
    int ls = atomicAdd(&hs[bs], 1);
    int ld2 = atomicAdd(&hd[bd], 1);
    srclist[cbS[bs] + ls] = s;
    elist[cbD[bd] + ld2] = (unsigned)s | ((unsigned)(d & 127) << 17);
  }
}

// Back kernel: [out-degree -> dinv | per-bucket counting sort -> CSR]
__global__ __launch_bounds__(256) void k_back(const int* __restrict__ sBase,
                                              const int* __restrict__ srclist,
                                              float* __restrict__ dinv,
                                              const int* __restrict__ dBase,
                                              const unsigned* __restrict__ elist,
                                              int* __restrict__ rowptr,
                                              int* __restrict__ adj) {
  __shared__ int cnt[128], sc[128], off[128], fill[128];
  int t = threadIdx.x;
  int bb = blockIdx.x;
  if (bb < NBK) {
    // ---- out-degree
    int b = bb;
    if (t < 128) cnt[t] = 0;
    __syncthreads();
    int e0 = sBase[b], e1 = sBase[b + 1];
    for (int i = e0 + t; i < e1; i += 256) atomicAdd(&cnt[srclist[i] & 127], 1);
    __syncthreads();
    if (t < 128) {
      int node = b * 128 + t;
      if (node < NN) {
        int c = cnt[t];
        dinv[node] = (c > 0) ? rsqrtf((float)c) : 0.f;
      }
    }
  } else {
    // ---- CSR counting sort
    int b = bb - NBK;
    if (t < 128) { cnt[t] = 0; fill[t] = 0; }
    __syncthreads();
    int e0 = dBase[b], e1 = dBase[b + 1];
    for (int i = e0 + t; i < e1; i += 256) atomicAdd(&cnt[elist[i] >> 17], 1);
    __syncthreads();
    if (t < 128) sc[t] = cnt[t];
    __syncthreads();
    for (int o = 1; o < 128; o <<= 1) {
      int a = (t < 128 && t >= o) ? sc[t - o] : 0;
      __syncthreads();
      if (t < 128) sc[t] += a;
      __syncthreads();
    }
    if (t < 128) {
      off[t] = sc[t] - cnt[t];  // exclusive
      int node = b * 128 + t;
      if (node < NN) rowptr[node] = e0 + off[t];
    }
    if (b == NBK - 1 && t == 0) rowptr[NN] = e1;
    __syncthreads();
    for (int i = e0 + t; i < e1; i += 256) {
      unsigned w2 = elist[i];
      int l = (int)(w2 >> 17);
      int pos = atomicAdd(&fill[l], 1);
      adj[e0 + off[l] + pos] = (int)(w2 & 0x1FFFFu);
    }
  }
}

// ---------------------------------------------------------------------------
// MFMA GEMM X: [128 nodes] x [K=128] x [N=192].
// Outputs: gV0 fp16 (cols 0..63), p01 packed half2 {dinv*U1, dinv*U2}.
static constexpr int AW = 136;  // LDS row stride (halves)
__global__ __launch_bounds__(256) void k_gemm_x(const float* __restrict__ x,
                                                const __half* __restrict__ BtX,
                                                const float* __restrict__ dinv,
                                                __half* __restrict__ gV0,
                                                unsigned* __restrict__ p01) {
  __shared__ __align__(16) _Float16 As[128 * AW];
  const int t = threadIdx.x;
  const int n0 = blockIdx.x * 128;
  {
    int i = t >> 1, q = t & 1;
    int row = n0 + i;
    _Float16* dst = As + i * AW + q * 64;
    if (row < NN) {
      const float* src = x + (size_t)row * 128 + q * 64;
#pragma unroll
      for (int c = 0; c < 64; c += 4) {
        float4 v = *reinterpret_cast<const float4*>(src + c);
        ushort4 u;
        u.x = __half_as_ushort(__float2half_rn(v.x));
        u.y = __half_as_ushort(__float2half_rn(v.y));
        u.z = __half_as_ushort(__float2half_rn(v.z));
        u.w = __half_as_ushort(__float2half_rn(v.w));
        *reinterpret_cast<ushort4*>(dst + c) = u;
      }
    } else {
#pragma unroll
      for (int c = 0; c < 64; c += 4)
        *reinterpret_cast<ushort4*>(dst + c) = make_ushort4(0, 0, 0, 0);
    }
  }
  __syncthreads();
  const int w = t >> 6, lane = t & 63;
  const int quad = lane >> 4, l = lane & 15;
  f4v acc[2][12];
#pragma unroll
  for (int mt = 0; mt < 2; ++mt)
#pragma unroll
    for (int nt = 0; nt < 12; ++nt) acc[mt][nt] = (f4v){0.f, 0.f, 0.f, 0.f};

#pragma unroll
  for (int ks = 0; ks < 4; ++ks) {
    int k0 = ks * 32 + quad * 8;
    h8 a0 = *reinterpret_cast<const h8*>(As + (w * 32 + l) * AW + k0);
    h8 a1 = *reinterpret_cast<const h8*>(As + (w * 32 + 16 + l) * AW + k0);
#pragma unroll
    for (int nt = 0; nt < 12; ++nt) {
      h8 b = *reinterpret_cast<const h8*>(BtX + (size_t)(nt * 16 + l) * 128 + k0);
      acc[0][nt] = __builtin_amdgcn_mfma_f32_16x16x32_f16(a0, b, acc[0][nt], 0, 0, 0);
      acc[1][nt] = __builtin_amdgcn_mfma_f32_16x16x32_f16(a1, b, acc[1][nt], 0, 0, 0);
    }
  }
#pragma unroll
  for (int mt = 0; mt < 2; ++mt) {
#pragma unroll
    for (int r = 0; r < 4; ++r) {
      int row = n0 + w * 32 + mt * 16 + quad * 4 + r;
      if (row < NN) {
        float dv = dinv[row];
#pragma unroll
        for (int nt2 = 0; nt2 < 4; ++nt2) {
          gV0[(size_t)row * 64 + nt2 * 16 + l] = __float2half_rn(acc[mt][nt2][r]);
          p01[(size_t)row * 64 + nt2 * 16 + l] =
              pk2(dv * acc[mt][4 + nt2][r], dv * acc[mt][8 + nt2][r]);
        }
      }
    }
  }
}

// ---------------------------------------------------------------------------
// Pair-gather propagation. Wave = 1 node, two 32-lane halves process two edges
// per VMEM instruction; lane dl covers dims {2dl, 2dl+1}.

// prop2p: packed {U1,U2} table (uint2 rows of 32). oA=-dv*S(U1), oB=-dv^2*S(U2).
__global__ __launch_bounds__(256) void k_prop2p(const int* __restrict__ rp,
                                                const int* __restrict__ adj,
                                                const uint2* __restrict__ vp,
                                                const float* __restrict__ dinv,
                                                unsigned* __restrict__ oA,
                                                unsigned* __restrict__ oB) {
  int node = blockIdx.x * 4 + (threadIdx.x >> 6);
  if (node >= NN) return;
  int lane = threadIdx.x & 63, half = lane >> 5, dl = lane & 31;
  int p0 = rp[node], p1 = rp[node + 1];
  float ax0 = 0.f, ay0 = 0.f, bx0 = 0.f, by0 = 0.f;
  float ax1 = 0.f, ay1 = 0.f, bx1 = 0.f, by1 = 0.f;
  int p = p0;
  int pA = (p0 + 3) & ~3;
  if (pA > p1) pA = p1;
  if (half == 0)
    for (int q = p; q < pA; ++q) {
      uint2 u = vp[(size_t)adj[q] * 32 + dl];
      float2 f = up2(u.x), g = up2(u.y);
      ax0 += f.x; bx0 += f.y; ay0 += g.x; by0 += g.y;
    }
  p = pA;
  for (; p + 8 <= p1; p += 8) {
    int4 e0 = *reinterpret_cast<const int4*>(adj + p);
    int4 e1 = *reinterpret_cast<const int4*>(adj + p + 4);
    int s0 = half ? e0.y : e0.x;
    int s1 = half ? e0.w : e0.z;
    int s2 = half ? e1.y : e1.x;
    int s3 = half ? e1.w : e1.z;
    uint2 u0 = vp[(size_t)s0 * 32 + dl];
    uint2 u1 = vp[(size_t)s1 * 32 + dl];
    uint2 u2 = vp[(size_t)s2 * 32 + dl];
    uint2 u3 = vp[(size_t)s3 * 32 + dl];
    { float2 f = up2(u0.x), g = up2(u0.y); ax0 += f.x; bx0 += f.y; ay0 += g.x; by0 += g.y; }
    { float2 f = up2(u1.x), g = up2(u1.y); ax1 += f.x; bx1 += f.y; ay1 += g.x; by1 += g.y; }
    { float2 f = up2(u2.x), g = up2(u2.y); ax0 += f.x; bx0 += f.y; ay0 += g.x; by0 += g.y; }
    { float2 f = up2(u3.x), g = up2(u3.y); ax1 += f.x; bx1 += f.y; ay1 += g.x; by1 += g.y; }
  }
  if (p + 4 <= p1) {
    int4 e = *reinterpret_cast<const int4*>(adj + p);
    int s0 = half ? e.y : e.x;
    int s1 = half ? e.w : e.z;
    uint2 u0 = vp[(size_t)s0 * 32 + dl];
    uint2 u1 = vp[(size_t)s1 * 32 + dl];
    { float2 f = up2(u0.x), g = up2(u0.y); ax0 += f.x; bx0 += f.y; ay0 += g.x; by0 += g.y; }
    { float2 f = up2(u1.x), g = up2(u1.y); ax1 += f.x; bx1 += f.y; ay1 += g.x; by1 += g.y; }
    p += 4;
  }
  if (half == 0)
    for (; p < p1; ++p) {
      uint2 u = vp[(size_t)adj[p] * 32 + dl];
      float2 f = up2(u.x), g = up2(u.y);
      ax1 += f.x; bx1 += f.y; ay1 += g.x; by1 += g.y;
    }
  float sax = ax0 + ax1, say = ay0 + ay1;
  float sbx = bx0 + bx1, sby = by0 + by1;
  sax += __shfl(sax, lane ^ 32);
  say += __shfl(say, lane ^ 32);
  sbx += __shfl(sbx, lane ^ 32);
  sby += __shfl(sby, lane ^ 32);
  if (half == 0) {
    float dv = dinv[node];
    size_t idx = (size_t)node * 32 + dl;
    oA[idx] = pk2(-dv * sax, -dv * say);
    oB[idx] = pk2(-dv * dv * sbx, -dv * dv * sby);
  }
}

// prop1: fp16 table (uint rows of 32). o_p = fp16(-dv*S), o_s = fp16(dv*o_p).
__global__ __launch_bounds__(256) void k_prop1(const int* __restrict__ rp,
                                               const int* __restrict__ adj,
                                               const unsigned* __restrict__ vin,
                                               const float* __restrict__ dinv,
                                               unsigned* __restrict__ o_p,
                                               unsigned* __restrict__ o_s) {
  int node = blockIdx.x * 4 + (threadIdx.x >> 6);
  if (node >= NN) return;
  int lane = threadIdx.x & 63, half = lane >> 5, dl = lane & 31;
  int p0 = rp[node], p1 = rp[node + 1];
  float ax0 = 0.f, ay0 = 0.f, ax1 = 0.f, ay1 = 0.f;
  int p = p0;
  int pA = (p0 + 3) & ~3;
  if (pA > p1) pA = p1;
  if (half == 0)
    for (int q = p; q < pA; ++q) {
      float2 f = up2(vin[(size_t)adj[q] * 32 + dl]);
      ax0 += f.x; ay0 += f.y;
    }
  p = pA;
  for (; p + 8 <= p1; p += 8) {
    int4 e0 = *reinterpret_cast<const int4*>(adj + p);
    int4 e1 = *reinterpret_cast<const int4*>(adj + p + 4);
    int s0 = half ? e0.y : e0.x;
    int s1 = half ? e0.w : e0.z;
    int s2 = half ? e1.y : e1.x;
    int s3 = half ? e1.w : e1.z;
    unsigned u0 = vin[(size_t)s0 * 32 + dl];
    unsigned u1 = vin[(size_t)s1 * 32 + dl];
    unsigned u2 = vin[(size_t)s2 * 32 + dl];
    unsigned u3 = vin[(size_t)s3 * 32 + dl];
    { float2 f = up2(u0); ax0 += f.x; ay0 += f.y; }
    { float2 f = up2(u1); ax1 += f.x; ay1 += f.y; }
    { float2 f = up2(u2); ax0 += f.x; ay0 += f.y; }
    { float2 f = up2(u3); ax1 += f.x; ay1 += f.y; }
  }
  if (p + 4 <= p1) {
    int4 e = *reinterpret_cast<const int4*>(adj + p);
    int s0 = half ? e.y : e.x;
    int s1 = half ? e.w : e.z;
    unsigned u0 = vin[(size_t)s0 * 32 + dl];
    unsigned u1 = vin[(size_t)s1 * 32 + dl];
    { float2 f = up2(u0); ax0 += f.x; ay0 += f.y; }
    { float2 f = up2(u1); ax1 += f.x; ay1 += f.y; }
    p += 4;
  }
  if (half == 0)
    for (; p < p1; ++p) {
      float2 f = up2(vin[(size_t)adj[p] * 32 + dl]);
      ax1 += f.x; ay1 += f.y;
    }
  float sx = ax0 + ax1, sy = ay0 + ay1;
  sx += __shfl(sx, lane ^ 32);
  sy += __shfl(sy, lane ^ 32);
  if (half == 0) {
    float dv = dinv[node];
    float px = -dv * sx, py = -dv * sy;
    size_t idx = (size_t)node * 32 + dl;
    o_p[idx] = pk2(px, py);
    if (o_s) o_s[idx] = pk2(dv * px, dv * py);
  }
}

// prop fused with h1: R = -dv*S(gQs); h1 = relu(V0 + P + 2R + b1); outputs fp16.
__global__ __launch_bounds__(256) void k_prop_h1(const int* __restrict__ rp,
                                                 const int* __restrict__ adj,
                                                 const unsigned* __restrict__ vin,
                                                 const float* __restrict__ dinv,
                                                 const unsigned* __restrict__ gV0u,
                                                 const unsigned* __restrict__ gPu,
                                                 const float* __restrict__ b1v,
                                                 unsigned* __restrict__ gH1u,
                                                 unsigned* __restrict__ gH1su) {
  int node = blockIdx.x * 4 + (threadIdx.x >> 6);
  if (node >= NN) return;
  int lane = threadIdx.x & 63, half = lane >> 5, dl = lane & 31;
  int p0 = rp[node], p1 = rp[node + 1];
  float ax0 = 0.f, ay0 = 0.f, ax1 = 0.f, ay1 = 0.f;
  int p = p0;
  int pA = (p0 + 3) & ~3;
  if (pA > p1) pA = p1;
  if (half == 0)
    for (int q = p; q < pA; ++q) {
      float2 f = up2(vin[(size_t)adj[q] * 32 + dl]);
      ax0 += f.x; ay0 += f.y;
    }
  p = pA;
  for (; p + 8 <= p1; p += 8) {
    int4 e0 = *reinterpret_cast<const int4*>(adj + p);
    int4 e1 = *reinterpret_cast<const int4*>(adj + p + 4);
    int s0 = half ? e0.y : e0.x;
    int s1 = half ? e0.w : e0.z;
    int s2 = half ? e1.y : e1.x;
    int s3 = half ? e1.w : e1.z;
    unsigned u0 = vin[(size_t)s0 * 32 + dl];
    unsigned u1 = vin[(size_t)s1 * 32 + dl];
    unsigned u2 = vin[(size_t)s2 * 32 + dl];
    unsigned u3 = vin[(size_t)s3 * 32 + dl];
    { float2 f = up2(u0); ax0 += f.x; ay0 += f.y; }
    { float2 f = up2(u1); ax1 += f.x; ay1 += f.y; }
    { float2 f = up2(u2); ax0 += f.x; ay0 += f.y; }
    { float2 f = up2(u3); ax1 += f.x; ay1 += f.y; }
  }
  if (p + 4 <= p1) {
    int4 e = *reinterpret_cast<const int4*>(adj + p);
    int s0 = half ? e.y : e.x;
    int s1 = half ? e.w : e.z;
    unsigned u0 = vin[(size_t)s0 * 32 + dl];
    unsigned u1 = vin[(size_t)s1 * 32 + dl];
    { float2 f = up2(u0); ax0 += f.x; ay0 += f.y; }
    { float2 f = up2(u1); ax1 += f.x; ay1 += f.y; }
    p += 4;
  }
  if (half == 0)
    for (; p < p1; ++p) {
      float2 f = up2(vin[(size_t)adj[p] * 32 + dl]);
      ax1 += f.x; ay1 += f.y;
    }
  float sx = ax0 + ax1, sy = ay0 + ay1;
  sx += __shfl(sx, lane ^ 32);
  sy += __shfl(sy, lane ^ 32);
  if (half == 0) {
    float dv = dinv[node];
    float Rx = -dv * sx, Ry = -dv * sy;
    size_t idx = (size_t)node * 32 + dl;
    float2 v0 = up2(gV0u[idx]);
    float2 pp = up2(gPu[idx]);
    float bx = b1v[2 * dl], by = b1v[2 * dl + 1];
    float hx = fmaxf(v0.x + pp.x + 2.f * Rx + bx, 0.f);
    float hy = fmaxf(v0.y + pp.y + 2.f * Ry + by, 0.f);
    gH1u[idx] = pk2(hx, hy);
    gH1su[idx] = pk2(dv * hx, dv * hy);
  }
}

// ---------------------------------------------------------------------------
// MFMA GEMM H2 + pool: A = [h1|T1|T2] (128 x 192 fp16), B = BtH (192 x 64),
// relu+bias into LDS, then segmented mean-pool numerator into pooled[].
static constexpr int HW = 200;  // LDS row stride (halves)
__global__ __launch_bounds__(256) void k_gemm_h2_pool(const __half* __restrict__ gH1,
                                                      const __half* __restrict__ gT1,
                                                      const __half* __restrict__ gT2,
                                                      const __half* __restrict__ BtH,
                                                      const float* __restrict__ b2v,
                                                      const int* __restrict__ b32,
                                                      float* __restrict__ pooled) {
  __shared__ __align__(16) char smem[128 * HW * 2];  // 51.2 KB
  __shared__ int gb[128];
  _Float16* As = reinterpret_cast<_Float16*>(smem);
  const int t = threadIdx.x;
  const int n0 = blockIdx.x * 128;
  if (t < 128) gb[t] = (n0 + t < NN) ? b32[n0 + t] : -1;
  for (int c = t; c < 128 * 24; c += 256) {
    int row = c / 24, seg = c % 24;
    int tb = seg >> 3, off = (seg & 7) * 8;
    int rowg = n0 + row;
    h8 v = (h8){0, 0, 0, 0, 0, 0, 0, 0};
    if (rowg < NN) {
      const __half* src = (tb == 0 ? gH1 : tb == 1 ? gT1 : gT2) + (size_t)rowg * 64 + off;
      v = *reinterpret_cast<const h8*>(src);
    }
    *reinterpret_cast<h8*>(As + row * HW + seg * 8) = v;
  }
  __syncthreads();
  const int w = t >> 6, lane = t & 63;
  const int quad = lane >> 4, l = lane & 15;
  f4v acc[2][4];
#pragma unroll
  for (int mt = 0; mt < 2; ++mt)
#pragma unroll
    for (int nt = 0; nt < 4; ++nt) acc[mt][nt] = (f4v){0.f, 0.f, 0.f, 0.f};
#pragma unroll
  for (int ks = 0; ks < 6; ++ks) {
    int k0 = ks * 32 + quad * 8;
    h8 a0 = *reinterpret_cast<const h8*>(As + (w * 32 + l) * HW + k0);
    h8 a1 = *reinterpret_cast<const h8*>(As + (w * 32 + 16 + l) * HW + k0);
#pragma unroll
    for (int nt = 0; nt < 4; ++nt) {
      h8 b = *reinterpret_cast<const h8*>(BtH + (size_t)(nt * 16 + l) * 192 + k0);
      acc[0][nt] = __builtin_amdgcn_mfma_f32_16x16x32_f16(a0, b, acc[0][nt], 0, 0, 0);
      acc[1][nt] = __builtin_amdgcn_mfma_f32_16x16x32_f16(a1, b, acc[1][nt], 0, 0, 0);
    }
  }
  __syncthreads();  // done reading As; reuse LDS as ht[128][68] f32
  float (*ht)[68] = reinterpret_cast<float (*)[68]>(smem);
#pragma unroll
  for (int mt = 0; mt < 2; ++mt)
#pragma unroll
    for (int r = 0; r < 4; ++r) {
      int rl = w * 32 + mt * 16 + quad * 4 + r;
#pragma unroll
      for (int nt = 0; nt < 4; ++nt) {
        int col = nt * 16 + l;
        ht[rl][col] = fmaxf(acc[mt][nt][r] + b2v[col], 0.f);
      }
    }
  __syncthreads();
  int rg = t >> 6;
  int d = t & 63;
  int base = rg * 32;
  int cur = -2;
  float s = 0.f;
  for (int i2 = 0; i2 < 32; ++i2) {
    int g = gb[base + i2];  // wave-uniform
    if (g != cur) {
      if (cur >= 0) atomAddF(&pooled[cur * 64 + d], s);
      s = 0.f;
      cur = g;
    }
    if (g >= 0) s += ht[base + i2][d];
  }
  if (cur >= 0) atomAddF(&pooled[cur * 64 + d], s);
}

// Final: out[g] = dot(pooled[g]/max(cnt,1), Wfc) + bfc
__global__ void k_out(const float* __restrict__ pooled, const int* __restrict__ gcnt,
                      const float* __restrict__ Wfc, const float* __restrict__ bfc,
                      float* __restrict__ out) {
  int g = blockIdx.x, t = threadIdx.x;  // 64 threads
  float v = pooled[g * 64 + t] * Wfc[t];
  int c = gcnt[g];
  v /= (float)(c > 0 ? c : 1);
  for (int off = 32; off > 0; off >>= 1) v += __shfl_down(v, off, 64);
  if (t == 0) out[g] = v + bfc[0];
}

// ---------------------------------------------------------------------------
extern "C" void kernel_launch(void* const* d_in, const int* in_sizes, int n_in,
                              void* d_out, int out_size, void* d_ws, size_t ws_size,
                              hipStream_t stream) {
  const float* x   = (const float*)d_in[0];
  const void*  ei  = d_in[1];
  const void*  bat = d_in[2];
  const float* W1  = (const float*)d_in[3];
  const float* b1v = (const float*)d_in[4];
  const float* W2  = (const float*)d_in[5];
  const float* b2v = (const float*)d_in[6];
  const float* Wfc = (const float*)d_in[7];
  const float* bfc = (const float*)d_in[8];
  float* out = (float*)d_out;

  char* w = (char*)d_ws;
  size_t o = 0;
  auto take = [&](size_t bytes) -> void* {
    void* p = w + o;
    o = (o + bytes + 255) & ~(size_t)255;
    return p;
  };
  int*      flag   = (int*)take(256);
  // ---- zero region start
  int*      gcnt   = (int*)take((size_t)NG * 4);
  float*    pooled = (float*)take((size_t)NG * 64 * 4);
  int*      sCnt   = (int*)take((size_t)(NBK + 2) * 4);
  int*      dCnt   = (int*)take((size_t)(NBK + 2) * 4);
  // ---- zero region end
  char*     zend   = w + o;
  int*      sBase  = (int*)take((size_t)(NBK + 2) * 4);
  int*      dBase  = (int*)take((size_t)(NBK + 2) * 4);
  int*      sCur   = (int*)take((size_t)(NBK + 2) * 4);
  int*      dCur   = (int*)take((size_t)(NBK + 2) * 4);
  int*      b32    = (int*)take((size_t)NN * 4);
  float*    dinv   = (float*)take((size_t)NN * 4);
  int*      rowptr = (int*)take((size_t)(NN + 2) * 4);
  int*      hsBlk  = (int*)take((size_t)256 * NBK * 4);
  int*      hdBlk  = (int*)take((size_t)256 * NBK * 4);
  int*      srclist= (int*)take((size_t)NE * 4);   // reused as adj after k_back
  unsigned* elist  = (unsigned*)take((size_t)NE * 4);
  __half*   BtX    = (__half*)take((size_t)192 * 128 * 2);
  __half*   BtH    = (__half*)take((size_t)64 * 192 * 2);
  __half*   gV0    = (__half*)take((size_t)NN * 64 * 2);
  unsigned* p01    = (unsigned*)take((size_t)NN * 64 * 4);
  __half*   gP     = (__half*)take((size_t)NN * 64 * 2);
  __half*   gQs    = (__half*)take((size_t)NN * 64 * 2);
  __half*   gH1    = (__half*)take((size_t)NN * 64 * 2);
  __half*   gH1s   = (__half*)take((size_t)NN * 64 * 2);
  __half*   gT1    = (__half*)take((size_t)NN * 64 * 2);
  __half*   gT1s   = (__half*)take((size_t)NN * 64 * 2);
  __half*   gT2    = (__half*)take((size_t)NN * 64 * 2);
  int*      adj    = srclist;  // alias: srclist dead after deg part of k_back
  (void)in_sizes; (void)n_in; (void)out_size; (void)ws_size;

  hipMemsetAsync(gcnt, 0, (size_t)(zend - (char*)gcnt), stream);

  k_detect<<<1, 64, 0, stream>>>((const int*)ei, flag);
  k_front<<<GB_BATCH + GB_PREPW + GB_HIST, 256, 0, stream>>>(
      bat, ei, flag, W1, W2, b32, gcnt, BtX, BtH, sCnt, dCnt, hsBlk, hdBlk);
  k_scan<<<1, 1024, 0, stream>>>(sCnt, dCnt, sBase, dBase, sCur, dCur);
  k_scatter<<<256, 256, 0, stream>>>(ei, flag, hsBlk, hdBlk, sCur, dCur, srclist, elist);
  k_back<<<2 * NBK, 256, 0, stream>>>(sBase, srclist, dinv, dBase, elist, rowptr, adj);

  const int gemm_grid = (NN + 127) / 128;  // 782
  const int prop_grid = (NN + 3) / 4;      // 25000

  // Layer 1
  k_gemm_x<<<gemm_grid, 256, 0, stream>>>(x, BtX, dinv, gV0, p01);
  k_prop2p<<<prop_grid, 256, 0, stream>>>(rowptr, adj, (const uint2*)p01, dinv,
                                          (unsigned*)gP, (unsigned*)gQs);
  k_prop_h1<<<prop_grid, 256, 0, stream>>>(rowptr, adj, (const unsigned*)gQs, dinv,
                                           (const unsigned*)gV0, (const unsigned*)gP,
                                           b1v, (unsigned*)gH1, (unsigned*)gH1s);
  // Layer 2
  k_prop1<<<prop_grid, 256, 0, stream>>>(rowptr, adj, (const unsigned*)gH1s, dinv,
                                         (unsigned*)gT1, (unsigned*)gT1s);
  k_prop1<<<prop_grid, 256, 0, stream>>>(rowptr, adj, (const unsigned*)gT1s, dinv,
                                         (unsigned*)gT2, nullptr);
  k_gemm_h2_pool<<<gemm_grid, 256, 0, stream>>>(gH1, gT1, gT2, BtH, b2v, b32, pooled);
  k_out<<<NG, 64, 0, stream>>>(pooled, gcnt, Wfc, bfc, out);
}